// Round 5
// baseline (266.475 us; speedup 1.0000x reference)
//
#include <hip/hip_runtime.h>
#include <cstdint>
#include <cstddef>

#define GLOBAL_AS __attribute__((address_space(1)))
#define LDS_AS __attribute__((address_space(3)))

typedef unsigned short u16;
typedef unsigned int u32;
typedef __bf16 bf16x8 __attribute__((ext_vector_type(8)));
typedef float f32x4 __attribute__((ext_vector_type(4)));

static constexpr int CDIM = 768;
static constexpr int NROWS = 8192;   // B*Lq == B*H*W

__device__ __forceinline__ u16 f2bf(float f) {
  union { float f; u32 u; } v; v.f = f;
  return (u16)((v.u + 0x7fffu + ((v.u >> 16) & 1u)) >> 16);   // RNE
}
__device__ __forceinline__ float bf2f(u16 h) {
  union { u32 u; float f; } v; v.u = ((u32)h) << 16;
  return v.f;
}
// Load element i of an external tensor whose dtype is runtime-detected: F=1 f32, F=0 bf16.
__device__ __forceinline__ float ldf(const void* p, size_t i, int F) {
  return F ? ((const float*)p)[i] : bf2f(((const u16*)p)[i]);
}
// async 16B/lane global->LDS; LDS dest = wave-uniform base + lane*16 [m97]
__device__ __forceinline__ void load_lds16(const u16* g, u16* l) {
  __builtin_amdgcn_global_load_lds((const GLOBAL_AS u32*)g, (LDS_AS u32*)l, 16, 0, 0);
}

// ---------------- dtype detection ----------------
__global__ __launch_bounds__(256) void detect_kernel(const u16* __restrict__ x, int* __restrict__ flag) {
  int t = threadIdx.x;
  int cnt = 0;
  for (int i = t; i < 16384; i += 256) {
    u16 v = x[i];
    if ((v & 0x7F80u) == 0x7F80u) cnt++;   // bf16 NaN/Inf pattern
  }
  #pragma unroll
  for (int m = 32; m >= 1; m >>= 1) cnt += __shfl_xor(cnt, m, 64);
  __shared__ int r[4];
  if ((t & 63) == 0) r[t >> 6] = cnt;
  __syncthreads();
  if (t == 0) flag[0] = (r[0] + r[1] + r[2] + r[3] > 4) ? 1 : 0;   // 1 = f32 inputs
}

// ---------------- fused LayerNorm, vectorized: 192 threads, one row/block ----------------
__global__ __launch_bounds__(192) void ln_kernel(
    const void* __restrict__ x, const void* __restrict__ feat,
    const void* __restrict__ qw, const void* __restrict__ qb,
    const void* __restrict__ fw, const void* __restrict__ fb,
    u16* __restrict__ qout, u16* __restrict__ fout, const int* __restrict__ flagp) {
  const int F = *flagp;
  int row = blockIdx.x;   // 0..16383
  const void *src, *w, *b; u16* dst; size_t base;
  if (row < NROWS) { src = x; base = (size_t)row*CDIM; w = qw; b = qb; dst = qout + base; }
  else { int r2 = row - NROWS; src = feat; base = (size_t)r2*CDIM; w = fw; b = fb; dst = fout + (size_t)r2*CDIM; }
  int t = threadIdx.x;     // 0..191, covers 4 elems each
  float v[4];
  if (F) {
    float4 q = ((const float4*)((const float*)src + base))[t];
    v[0]=q.x; v[1]=q.y; v[2]=q.z; v[3]=q.w;
  } else {
    const u16* sp = (const u16*)src + base + t*4;
    v[0]=bf2f(sp[0]); v[1]=bf2f(sp[1]); v[2]=bf2f(sp[2]); v[3]=bf2f(sp[3]);
  }
  float s = v[0]+v[1]+v[2]+v[3];
  float sq = v[0]*v[0]+v[1]*v[1]+v[2]*v[2]+v[3]*v[3];
  #pragma unroll
  for (int m = 32; m >= 1; m >>= 1) { s += __shfl_xor(s, m, 64); sq += __shfl_xor(sq, m, 64); }
  __shared__ float red[6];
  int lane = t & 63, wv = t >> 6;
  if (lane == 0) { red[wv] = s; red[wv+3] = sq; }
  __syncthreads();
  s  = red[0]+red[1]+red[2];
  sq = red[3]+red[4]+red[5];
  float mean = s * (1.f/768.f);
  float var  = fmaxf(sq * (1.f/768.f) - mean*mean, 0.f);
  float inv  = rsqrtf(var + 1e-6f);
  u16 o[4];
  #pragma unroll
  for (int k = 0; k < 4; ++k) {
    float wk = ldf(w, t*4+k, F), bk = ldf(b, t*4+k, F);
    o[k] = f2bf((v[k]-mean)*inv*wk + bk);
  }
  *(ushort4*)(dst + t*4) = make_ushort4(o[0], o[1], o[2], o[3]);
}

// ---------------- transpose weights [K=768][N=768] -> [N][K], to bf16 ----------------
__global__ __launch_bounds__(256) void transpose_wt(
    const void* __restrict__ wv_, const void* __restrict__ wo_,
    u16* __restrict__ wvT, u16* __restrict__ woT, const int* __restrict__ flagp) {
  const int F = *flagp;
  __shared__ u16 tile[32][33];
  const void* in = blockIdx.z ? wo_ : wv_;
  u16* out       = blockIdx.z ? woT : wvT;
  int bn = blockIdx.x * 32;
  int bk = blockIdx.y * 32;
  int tx = threadIdx.x & 31, ty = threadIdx.x >> 5;
  #pragma unroll
  for (int i = ty; i < 32; i += 8)
    tile[i][tx] = F ? f2bf(((const float*)in)[(size_t)(bk+i)*CDIM + bn + tx])
                    : ((const u16*)in)[(size_t)(bk+i)*CDIM + bn + tx];
  __syncthreads();
  #pragma unroll
  for (int i = ty; i < 32; i += 8)
    out[(size_t)(bn+i)*CDIM + bk + tx] = tile[tx][i];
}

// ---------------- build padded [128][768] B^T for [w_off | w_attn | 0], bf16 ----------------
__global__ __launch_bounds__(256) void build_woffaw(
    const void* __restrict__ woff, const void* __restrict__ wattn, u16* __restrict__ outT,
    const int* __restrict__ flagp) {
  const int F = *flagp;
  int idx = blockIdx.x * 256 + threadIdx.x;
  if (idx >= 128 * CDIM) return;
  int n = idx / CDIM, k = idx - n*CDIM;
  float v = 0.f;
  if (n < 48)      v = ldf(woff, (size_t)k*48 + n, F);
  else if (n < 72) v = ldf(wattn, (size_t)k*24 + (n-48), F);
  outT[idx] = f2bf(v);
}

// ---------------- MFMA GEMM: C[M,N] = A[M,768]*Bt[N,768]^T, tile 128x64, BK=32 ----------------
// m97-style: unpadded [row][32] LDS tiles, global_load_lds width-16 staging.
// grid (M/128, N/64, KS).  EPI 0: bf16 C+bias.  EPI 1: f32 K-partials [z][M][72], bias in z==0.
// EPI 2: out = x + gamma*(C + bias), dtype per flag.
template<int EPI>
__global__ __launch_bounds__(256) void gemm_bt(
    const u16* __restrict__ A, const u16* __restrict__ Bt, void* __restrict__ Cout,
    const void* __restrict__ bias0, const void* __restrict__ bias1,
    const void* __restrict__ xres, const void* __restrict__ gammap,
    const int* __restrict__ flagp) {
  const int F = *flagp;
  __shared__ __align__(16) u16 smem[8192];   // 16 KB: As[128][32] | Bs[64][32]; Cs[128][64] aliases all
  u16* As = smem;            // 4096 u16
  u16* Bs = smem + 4096;     // 2048 u16
  u16* Cs = smem;            // 8192 u16 (epilogue)
  const int m0 = blockIdx.x * 128;
  const int n0 = blockIdx.y * 64;
  const int t = threadIdx.x, lane = t & 63, wv = t >> 6;
  const int wm = wv & 1, wn = wv >> 1;
  const int kChunk = CDIM / gridDim.z;
  const int kbase = blockIdx.z * kChunk;
  const int lrow = lane >> 2;        // 0..15 row within 16-row segment
  const int lcol = (lane & 3) * 8;   // u16 col within 32-wide row
  f32x4 acc[4][2] = {};

  for (int k0 = kbase; k0 < kbase + kChunk; k0 += 32) {
    // A: 8 segments of 16 rows (2 per wave); B: 4 segments (1 per wave). 1KB each.
    load_lds16(A  + (size_t)(m0 + (wv*2  )*16 + lrow)*CDIM + k0 + lcol, As + (wv*2  )*512);
    load_lds16(A  + (size_t)(m0 + (wv*2+1)*16 + lrow)*CDIM + k0 + lcol, As + (wv*2+1)*512);
    load_lds16(Bt + (size_t)(n0 +  wv    *16 + lrow)*CDIM + k0 + lcol, Bs +  wv    *512);
    __syncthreads();
    bf16x8 af[4], bfr[2];
    const int kc = (lane >> 4) * 8;
    #pragma unroll
    for (int i = 0; i < 4; ++i)
      af[i]  = *(const bf16x8*)(As + (wm*64 + i*16 + (lane & 15))*32 + kc);
    #pragma unroll
    for (int j = 0; j < 2; ++j)
      bfr[j] = *(const bf16x8*)(Bs + (wn*32 + j*16 + (lane & 15))*32 + kc);
    #pragma unroll
    for (int i = 0; i < 4; ++i)
      #pragma unroll
      for (int j = 0; j < 2; ++j)
        acc[i][j] = __builtin_amdgcn_mfma_f32_16x16x32_bf16(af[i], bfr[j], acc[i][j], 0, 0, 0);
    __syncthreads();
  }

  const int r0 = (lane >> 4) * 4;    // C/D: col=lane&15, row=(lane>>4)*4+reg  [m89/m91]
  const int c  = lane & 15;

  if (EPI == 1) {                    // scattered f32 partial stores (only 72 cols live)
    float* op = (float*)Cout + (size_t)blockIdx.z * NROWS * 72;
    #pragma unroll
    for (int i = 0; i < 4; ++i)
      #pragma unroll
      for (int j = 0; j < 2; ++j) {
        int col = n0 + wn*32 + j*16 + c;
        if (col < 72) {
          float bb = 0.f;
          if (blockIdx.z == 0) bb = (col < 48) ? ldf(bias0, col, F) : ldf(bias1, col-48, F);
          #pragma unroll
          for (int r = 0; r < 4; ++r)
            op[(size_t)(m0 + wm*64 + i*16 + r0 + r)*72 + col] = acc[i][j][r] + bb;
        }
      }
    return;
  }

  // stage (acc + bias) as bf16 into Cs, then coalesced 16B stores
  #pragma unroll
  for (int i = 0; i < 4; ++i)
    #pragma unroll
    for (int j = 0; j < 2; ++j) {
      int col = wn*32 + j*16 + c;
      float bb = ldf(bias0, n0 + col, F);
      #pragma unroll
      for (int r = 0; r < 4; ++r)
        Cs[(wm*64 + i*16 + r0 + r)*64 + col] = f2bf(acc[i][j][r] + bb);
    }
  __syncthreads();
  #pragma unroll
  for (int it = 0; it < 4; ++it) {
    int idx = it*256 + t;            // 0..1023, 16B each -> 128x64 u16 tile
    int row = idx >> 3, colb = (idx & 7) * 8;
    size_t gbase = (size_t)(m0 + row)*CDIM + n0 + colb;
    const u16* cp = Cs + row*64 + colb;
    if (EPI == 0) {
      *(bf16x8*)((u16*)Cout + gbase) = *(const bf16x8*)cp;
    } else {                          // EPI 2
      if (F) {
        const float* xp = (const float*)xres + gbase;
        const float* gp = (const float*)gammap + n0 + colb;
        float4 x0 = *(const float4*)xp,      x1 = *(const float4*)(xp + 4);
        float4 g0 = *(const float4*)gp,      g1 = *(const float4*)(gp + 4);
        float4 o0, o1;
        o0.x = x0.x + g0.x*bf2f(cp[0]); o0.y = x0.y + g0.y*bf2f(cp[1]);
        o0.z = x0.z + g0.z*bf2f(cp[2]); o0.w = x0.w + g0.w*bf2f(cp[3]);
        o1.x = x1.x + g1.x*bf2f(cp[4]); o1.y = x1.y + g1.y*bf2f(cp[5]);
        o1.z = x1.z + g1.z*bf2f(cp[6]); o1.w = x1.w + g1.w*bf2f(cp[7]);
        *(float4*)((float*)Cout + gbase)     = o0;
        *(float4*)((float*)Cout + gbase + 4) = o1;
      } else {
        const u16* xp = (const u16*)xres + gbase;
        const u16* gp = (const u16*)gammap + n0 + colb;
        u16 ov[8];
        #pragma unroll
        for (int k = 0; k < 8; ++k)
          ov[k] = f2bf(bf2f(xp[k]) + bf2f(gp[k]) * bf2f(cp[k]));
        *(bf16x8*)((u16*)Cout + gbase) = *(const bf16x8*)ov;
      }
    }
  }
}

// ---------------- deformable sampling: one block per row (6 waves = 6 heads) ----------------
__global__ __launch_bounds__(384) void sample_kernel(
    const u16* __restrict__ value,   // [B*4096][768] bf16, col = h*128+d
    const float* __restrict__ offawp,// [2][8192][72] f32 K-partials
    const void* __restrict__ refp,   // [8192][2] external dtype
    u16* __restrict__ out, const int* __restrict__ flagp) {
  const int F = *flagp;
  const int row  = blockIdx.x;          // 0..8191
  const int h    = threadIdx.x >> 6;    // 0..5
  const int lane = threadIdx.x & 63;
  const int b    = row >> 12;
  const float* p0 = offawp + (size_t)row*72;
  const float* p1 = p0 + (size_t)NROWS*72;
  float ob[8], aw4[4];
  #pragma unroll
  for (int k = 0; k < 8; ++k) ob[k] = p0[h*8+k] + p1[h*8+k];
  #pragma unroll
  for (int k = 0; k < 4; ++k) aw4[k] = p0[48+h*4+k] + p1[48+h*4+k];
  float rx = ldf(refp, (size_t)row*2,   F) * 64.f - 0.5f;
  float ry = ldf(refp, (size_t)row*2+1, F) * 64.f - 0.5f;
  float mx = fmaxf(fmaxf(aw4[0],aw4[1]), fmaxf(aw4[2],aw4[3]));
  float e0 = __expf(aw4[0]-mx), e1 = __expf(aw4[1]-mx), e2 = __expf(aw4[2]-mx), e3 = __expf(aw4[3]-mx);
  float rs = 1.f / (e0+e1+e2+e3);
  float awt[4] = {e0*rs, e1*rs, e2*rs, e3*rs};
  const u32* vb = (const u32*)value + (size_t)b*4096*384 + h*64 + lane;
  float accx = 0.f, accy = 0.f;
  #pragma unroll
  for (int p = 0; p < 4; ++p) {
    float px = rx + ob[p*2];
    float py = ry + ob[p*2+1];
    float x0f = floorf(px), y0f = floorf(py);
    float fx = px - x0f, fy = py - y0f;
    int x0 = (int)x0f, y0 = (int)y0f;
    #pragma unroll
    for (int dy = 0; dy < 2; ++dy) {
      #pragma unroll
      for (int dx = 0; dx < 2; ++dx) {
        int yi = y0 + dy, xi = x0 + dx;
        float wt = (dy ? fy : 1.f-fy) * (dx ? fx : 1.f-fx) * awt[p];
        if (yi < 0 || yi >= 64 || xi < 0 || xi >= 64) wt = 0.f;
        if (wt != 0.f) {                       // wave-uniform
          u32 v = vb[(size_t)(yi*64 + xi) * 384];
          accx += wt * bf2f((u16)(v & 0xffffu));
          accy += wt * bf2f((u16)(v >> 16));
        }
      }
    }
  }
  ((u32*)out)[(size_t)row*384 + h*64 + lane] = (u32)f2bf(accx) | ((u32)f2bf(accy) << 16);
}

extern "C" void kernel_launch(void* const* d_in, const int* in_sizes, int n_in,
                              void* d_out, int out_size, void* d_ws, size_t ws_size,
                              hipStream_t stream) {
  const void* x       = d_in[0];
  const void* refp    = d_in[1];
  const void* feat    = d_in[2];
  const void* qn_w    = d_in[5];
  const void* qn_b    = d_in[6];
  const void* fn_w    = d_in[7];
  const void* fn_b    = d_in[8];
  const void* gamma   = d_in[9];
  const void* w_value = d_in[10];
  const void* b_value = d_in[11];
  const void* w_off   = d_in[12];
  const void* b_off   = d_in[13];
  const void* w_attn  = d_in[14];
  const void* b_attn  = d_in[15];
  const void* w_out   = d_in[16];
  const void* b_out   = d_in[17];

  char* p = (char*)d_ws;
  const size_t act = (size_t)NROWS * CDIM * 2;       // 12.58 MB
  u16* q_bf   = (u16*)p; p += act;
  u16* f_bf   = (u16*)p; p += act;
  u16* val_bf = (u16*)p; p += act;
  u16* wvT    = (u16*)p; p += (size_t)CDIM*CDIM*2;
  u16* woT    = (u16*)p; p += (size_t)CDIM*CDIM*2;
  u16* woaT   = (u16*)p; p += (size_t)128*CDIM*2;
  float* offawp = (float*)p; p += (size_t)2*NROWS*72*4;
  int* dflag  = (int*)p; p += 256;
  u16* samp_bf = q_bf;   // q_bf dead after gemm_bt<1>; reuse

  detect_kernel<<<dim3(1), 256, 0, stream>>>((const u16*)x, dflag);
  transpose_wt<<<dim3(24,24,2), 256, 0, stream>>>(w_value, w_out, wvT, woT, dflag);
  build_woffaw<<<dim3(384), 256, 0, stream>>>(w_off, w_attn, woaT, dflag);
  ln_kernel<<<dim3(16384), 192, 0, stream>>>(x, feat, qn_w, qn_b, fn_w, fn_b, q_bf, f_bf, dflag);
  gemm_bt<0><<<dim3(64,12,1), 256, 0, stream>>>(f_bf, wvT, val_bf, b_value, nullptr, nullptr, nullptr, dflag);
  gemm_bt<1><<<dim3(64,2,2),  256, 0, stream>>>(q_bf, woaT, offawp, b_off, b_attn, nullptr, nullptr, dflag);
  sample_kernel<<<dim3(8192), 384, 0, stream>>>(val_bf, offawp, refp, samp_bf, dflag);
  gemm_bt<2><<<dim3(64,12,1), 256, 0, stream>>>(samp_bf, woT, d_out, b_out, nullptr, x, gamma, dflag);
}

// Round 6
// 245.677 us; speedup vs baseline: 1.0847x; 1.0847x over previous
//
#include <hip/hip_runtime.h>
#include <cstdint>
#include <cstddef>

#define GLOBAL_AS __attribute__((address_space(1)))
#define LDS_AS __attribute__((address_space(3)))

typedef unsigned short u16;
typedef unsigned int u32;
typedef __bf16 bf16x8 __attribute__((ext_vector_type(8)));
typedef float f32x4 __attribute__((ext_vector_type(4)));

static constexpr int CDIM = 768;
static constexpr int NROWS = 8192;   // B*Lq == B*H*W

__device__ __forceinline__ u16 f2bf(float f) {
  union { float f; u32 u; } v; v.f = f;
  return (u16)((v.u + 0x7fffu + ((v.u >> 16) & 1u)) >> 16);   // RNE
}
__device__ __forceinline__ float bf2f(u16 h) {
  union { u32 u; float f; } v; v.u = ((u32)h) << 16;
  return v.f;
}
// Load element i of an external tensor whose dtype is runtime-detected: F=1 f32, F=0 bf16.
__device__ __forceinline__ float ldf(const void* p, size_t i, int F) {
  return F ? ((const float*)p)[i] : bf2f(((const u16*)p)[i]);
}
// async 16B/lane global->LDS; LDS dest = wave-uniform base + lane*16 [m97]
__device__ __forceinline__ void load_lds16(const u16* g, u16* l) {
  __builtin_amdgcn_global_load_lds((const GLOBAL_AS u32*)g, (LDS_AS u32*)l, 16, 0, 0);
}

// ---------------- dtype detection ----------------
__global__ __launch_bounds__(256) void detect_kernel(const u16* __restrict__ x, int* __restrict__ flag) {
  int t = threadIdx.x;
  int cnt = 0;
  for (int i = t; i < 16384; i += 256) {
    u16 v = x[i];
    if ((v & 0x7F80u) == 0x7F80u) cnt++;   // bf16 NaN/Inf pattern
  }
  #pragma unroll
  for (int m = 32; m >= 1; m >>= 1) cnt += __shfl_xor(cnt, m, 64);
  __shared__ int r[4];
  if ((t & 63) == 0) r[t >> 6] = cnt;
  __syncthreads();
  if (t == 0) flag[0] = (r[0] + r[1] + r[2] + r[3] > 4) ? 1 : 0;   // 1 = f32 inputs
}

// ---------------- fused LayerNorm, vectorized: 192 threads, one row/block ----------------
__global__ __launch_bounds__(192) void ln_kernel(
    const void* __restrict__ x, const void* __restrict__ feat,
    const void* __restrict__ qw, const void* __restrict__ qb,
    const void* __restrict__ fw, const void* __restrict__ fb,
    u16* __restrict__ qout, u16* __restrict__ fout, const int* __restrict__ flagp) {
  const int F = *flagp;
  int row = blockIdx.x;   // 0..16383
  const void *src, *w, *b; u16* dst; size_t base;
  if (row < NROWS) { src = x; base = (size_t)row*CDIM; w = qw; b = qb; dst = qout + base; }
  else { int r2 = row - NROWS; src = feat; base = (size_t)r2*CDIM; w = fw; b = fb; dst = fout + (size_t)r2*CDIM; }
  int t = threadIdx.x;     // 0..191, covers 4 elems each
  float v[4];
  if (F) {
    float4 q = ((const float4*)((const float*)src + base))[t];
    v[0]=q.x; v[1]=q.y; v[2]=q.z; v[3]=q.w;
  } else {
    const u16* sp = (const u16*)src + base + t*4;
    v[0]=bf2f(sp[0]); v[1]=bf2f(sp[1]); v[2]=bf2f(sp[2]); v[3]=bf2f(sp[3]);
  }
  float s = v[0]+v[1]+v[2]+v[3];
  float sq = v[0]*v[0]+v[1]*v[1]+v[2]*v[2]+v[3]*v[3];
  #pragma unroll
  for (int m = 32; m >= 1; m >>= 1) { s += __shfl_xor(s, m, 64); sq += __shfl_xor(sq, m, 64); }
  __shared__ float red[6];
  int lane = t & 63, wv = t >> 6;
  if (lane == 0) { red[wv] = s; red[wv+3] = sq; }
  __syncthreads();
  s  = red[0]+red[1]+red[2];
  sq = red[3]+red[4]+red[5];
  float mean = s * (1.f/768.f);
  float var  = fmaxf(sq * (1.f/768.f) - mean*mean, 0.f);
  float inv  = rsqrtf(var + 1e-6f);
  u16 o[4];
  #pragma unroll
  for (int k = 0; k < 4; ++k) {
    float wk = ldf(w, t*4+k, F), bk = ldf(b, t*4+k, F);
    o[k] = f2bf((v[k]-mean)*inv*wk + bk);
  }
  *(ushort4*)(dst + t*4) = make_ushort4(o[0], o[1], o[2], o[3]);
}

// ---------------- transpose weights [K=768][N=768] -> [N][K], to bf16 ----------------
__global__ __launch_bounds__(256) void transpose_wt(
    const void* __restrict__ wv_, const void* __restrict__ wo_,
    u16* __restrict__ wvT, u16* __restrict__ woT, const int* __restrict__ flagp) {
  const int F = *flagp;
  __shared__ u16 tile[32][33];
  const void* in = blockIdx.z ? wo_ : wv_;
  u16* out       = blockIdx.z ? woT : wvT;
  int bn = blockIdx.x * 32;
  int bk = blockIdx.y * 32;
  int tx = threadIdx.x & 31, ty = threadIdx.x >> 5;
  #pragma unroll
  for (int i = ty; i < 32; i += 8)
    tile[i][tx] = F ? f2bf(((const float*)in)[(size_t)(bk+i)*CDIM + bn + tx])
                    : ((const u16*)in)[(size_t)(bk+i)*CDIM + bn + tx];
  __syncthreads();
  #pragma unroll
  for (int i = ty; i < 32; i += 8)
    out[(size_t)(bn+i)*CDIM + bk + tx] = tile[tx][i];
}

// ---------------- build padded [128][768] B^T for [w_off | w_attn | 0], bf16 ----------------
__global__ __launch_bounds__(256) void build_woffaw(
    const void* __restrict__ woff, const void* __restrict__ wattn, u16* __restrict__ outT,
    const int* __restrict__ flagp) {
  const int F = *flagp;
  int idx = blockIdx.x * 256 + threadIdx.x;
  if (idx >= 128 * CDIM) return;
  int n = idx / CDIM, k = idx - n*CDIM;
  float v = 0.f;
  if (n < 48)      v = ldf(woff, (size_t)k*48 + n, F);
  else if (n < 72) v = ldf(wattn, (size_t)k*24 + (n-48), F);
  outT[idx] = f2bf(v);
}

// ---------------- MFMA GEMM: C[M,N] = A[M,768]*Bt[N,768]^T, tile 128x64, BK=32 ----------------
// m97-style: unpadded [row][32] LDS tiles, global_load_lds width-16 staging.
// grid (M/128, N/64, KS).  EPI 0: bf16 C+bias.  EPI 1: f32 K-partials [z][M][72], bias in z==0.
// EPI 2: out = x + gamma*(C + bias), dtype per flag.
template<int EPI>
__global__ __launch_bounds__(256) void gemm_bt(
    const u16* __restrict__ A, const u16* __restrict__ Bt, void* __restrict__ Cout,
    const void* __restrict__ bias0, const void* __restrict__ bias1,
    const void* __restrict__ xres, const void* __restrict__ gammap,
    const int* __restrict__ flagp) {
  const int F = *flagp;
  __shared__ __align__(16) u16 smem[8192];   // 16 KB: As[128][32] | Bs[64][32]; Cs[128][64] aliases all
  u16* As = smem;            // 4096 u16
  u16* Bs = smem + 4096;     // 2048 u16
  u16* Cs = smem;            // 8192 u16 (epilogue)
  const int m0 = blockIdx.x * 128;
  const int n0 = blockIdx.y * 64;
  const int t = threadIdx.x, lane = t & 63, wv = t >> 6;
  const int wm = wv & 1, wn = wv >> 1;
  const int kChunk = CDIM / gridDim.z;
  const int kbase = blockIdx.z * kChunk;
  const int lrow = lane >> 2;        // 0..15 row within 16-row segment
  const int lcol = (lane & 3) * 8;   // u16 col within 32-wide row
  f32x4 acc[4][2] = {};

  for (int k0 = kbase; k0 < kbase + kChunk; k0 += 32) {
    // A: 8 segments of 16 rows (2 per wave); B: 4 segments (1 per wave). 1KB each.
    load_lds16(A  + (size_t)(m0 + (wv*2  )*16 + lrow)*CDIM + k0 + lcol, As + (wv*2  )*512);
    load_lds16(A  + (size_t)(m0 + (wv*2+1)*16 + lrow)*CDIM + k0 + lcol, As + (wv*2+1)*512);
    load_lds16(Bt + (size_t)(n0 +  wv    *16 + lrow)*CDIM + k0 + lcol, Bs +  wv    *512);
    __syncthreads();
    bf16x8 af[4], bfr[2];
    const int kc = (lane >> 4) * 8;
    #pragma unroll
    for (int i = 0; i < 4; ++i)
      af[i]  = *(const bf16x8*)(As + (wm*64 + i*16 + (lane & 15))*32 + kc);
    #pragma unroll
    for (int j = 0; j < 2; ++j)
      bfr[j] = *(const bf16x8*)(Bs + (wn*32 + j*16 + (lane & 15))*32 + kc);
    #pragma unroll
    for (int i = 0; i < 4; ++i)
      #pragma unroll
      for (int j = 0; j < 2; ++j)
        acc[i][j] = __builtin_amdgcn_mfma_f32_16x16x32_bf16(af[i], bfr[j], acc[i][j], 0, 0, 0);
    __syncthreads();
  }

  const int r0 = (lane >> 4) * 4;    // C/D: col=lane&15, row=(lane>>4)*4+reg  [m89/m91]
  const int c  = lane & 15;

  if (EPI == 1) {                    // scattered f32 partial stores (only 72 cols live)
    float* op = (float*)Cout + (size_t)blockIdx.z * NROWS * 72;
    #pragma unroll
    for (int i = 0; i < 4; ++i)
      #pragma unroll
      for (int j = 0; j < 2; ++j) {
        int col = n0 + wn*32 + j*16 + c;
        if (col < 72) {
          float bb = 0.f;
          if (blockIdx.z == 0) bb = (col < 48) ? ldf(bias0, col, F) : ldf(bias1, col-48, F);
          #pragma unroll
          for (int r = 0; r < 4; ++r)
            op[(size_t)(m0 + wm*64 + i*16 + r0 + r)*72 + col] = acc[i][j][r] + bb;
        }
      }
    return;
  }

  // stage (acc + bias) as bf16 into Cs, then coalesced 16B stores
  #pragma unroll
  for (int i = 0; i < 4; ++i)
    #pragma unroll
    for (int j = 0; j < 2; ++j) {
      int col = wn*32 + j*16 + c;
      float bb = ldf(bias0, n0 + col, F);
      #pragma unroll
      for (int r = 0; r < 4; ++r)
        Cs[(wm*64 + i*16 + r0 + r)*64 + col] = f2bf(acc[i][j][r] + bb);
    }
  __syncthreads();
  #pragma unroll
  for (int it = 0; it < 4; ++it) {
    int idx = it*256 + t;            // 0..1023, 16B each -> 128x64 u16 tile
    int row = idx >> 3, colb = (idx & 7) * 8;
    size_t gbase = (size_t)(m0 + row)*CDIM + n0 + colb;
    const u16* cp = Cs + row*64 + colb;
    if (EPI == 0) {
      *(bf16x8*)((u16*)Cout + gbase) = *(const bf16x8*)cp;
    } else {                          // EPI 2
      if (F) {
        const float* xp = (const float*)xres + gbase;
        const float* gp = (const float*)gammap + n0 + colb;
        float4 x0 = *(const float4*)xp,      x1 = *(const float4*)(xp + 4);
        float4 g0 = *(const float4*)gp,      g1 = *(const float4*)(gp + 4);
        float4 o0, o1;
        o0.x = x0.x + g0.x*bf2f(cp[0]); o0.y = x0.y + g0.y*bf2f(cp[1]);
        o0.z = x0.z + g0.z*bf2f(cp[2]); o0.w = x0.w + g0.w*bf2f(cp[3]);
        o1.x = x1.x + g1.x*bf2f(cp[4]); o1.y = x1.y + g1.y*bf2f(cp[5]);
        o1.z = x1.z + g1.z*bf2f(cp[6]); o1.w = x1.w + g1.w*bf2f(cp[7]);
        *(float4*)((float*)Cout + gbase)     = o0;
        *(float4*)((float*)Cout + gbase + 4) = o1;
      } else {
        const u16* xp = (const u16*)xres + gbase;
        const u16* gp = (const u16*)gammap + n0 + colb;
        u16 ov[8];
        #pragma unroll
        for (int k = 0; k < 8; ++k)
          ov[k] = f2bf(bf2f(xp[k]) + bf2f(gp[k]) * bf2f(cp[k]));
        *(bf16x8*)((u16*)Cout + gbase) = *(const bf16x8*)ov;
      }
    }
  }
}

// ---------------- deformable sampling: wave per (row,head); branch-free 16-load burst ----------------
__global__ __launch_bounds__(256) void sample_kernel(
    const u16* __restrict__ value,   // [B*4096][768] bf16, col = h*128+d
    const float* __restrict__ offawp,// [2][8192][72] f32 K-partials
    const void* __restrict__ refp,   // [8192][2] external dtype
    u16* __restrict__ out, const int* __restrict__ flagp) {
  const int F = *flagp;
  const int wid  = blockIdx.x * 4 + (threadIdx.x >> 6);  // 0..49151
  const int lane = threadIdx.x & 63;
  const int h   = wid % 6;
  const int row = wid / 6;
  const int b   = row >> 12;
  const float* p0 = offawp + (size_t)row*72;
  const float* p1 = p0 + (size_t)NROWS*72;
  float ob[8], aw4[4];
  #pragma unroll
  for (int k = 0; k < 8; ++k) ob[k] = p0[h*8+k] + p1[h*8+k];
  #pragma unroll
  for (int k = 0; k < 4; ++k) aw4[k] = p0[48+h*4+k] + p1[48+h*4+k];
  float rx = ldf(refp, (size_t)row*2,   F) * 64.f - 0.5f;
  float ry = ldf(refp, (size_t)row*2+1, F) * 64.f - 0.5f;
  float mx = fmaxf(fmaxf(aw4[0],aw4[1]), fmaxf(aw4[2],aw4[3]));
  float e0 = __expf(aw4[0]-mx), e1 = __expf(aw4[1]-mx), e2 = __expf(aw4[2]-mx), e3 = __expf(aw4[3]-mx);
  float rs = 1.f / (e0+e1+e2+e3);
  float awt[4] = {e0*rs, e1*rs, e2*rs, e3*rs};

  // Precompute all 16 (offset, weight) pairs: clamp coords, zero invalid weights.
  float wts[16]; int offs[16];
  #pragma unroll
  for (int p = 0; p < 4; ++p) {
    float px = rx + ob[p*2];
    float py = ry + ob[p*2+1];
    float x0f = floorf(px), y0f = floorf(py);
    float fx = px - x0f, fy = py - y0f;
    int x0 = (int)x0f, y0 = (int)y0f;
    #pragma unroll
    for (int dy = 0; dy < 2; ++dy)
      #pragma unroll
      for (int dx = 0; dx < 2; ++dx) {
        int yi = y0 + dy, xi = x0 + dx;
        bool valid = (yi >= 0) & (yi < 64) & (xi >= 0) & (xi < 64);
        float wt = (dy ? fy : 1.f-fy) * (dx ? fx : 1.f-fx) * awt[p];
        wts[p*4+dy*2+dx] = valid ? wt : 0.f;
        int yc = min(max(yi, 0), 63), xc = min(max(xi, 0), 63);
        offs[p*4+dy*2+dx] = (yc*64 + xc) * 384;
      }
  }
  const u32* vb = (const u32*)value + (size_t)b*4096*384 + h*64 + lane;
  u32 vals[16];
  #pragma unroll
  for (int i = 0; i < 16; ++i) vals[i] = vb[offs[i]];   // 16 loads in flight
  float accx = 0.f, accy = 0.f;
  #pragma unroll
  for (int i = 0; i < 16; ++i) {
    accx += wts[i] * bf2f((u16)(vals[i] & 0xffffu));
    accy += wts[i] * bf2f((u16)(vals[i] >> 16));
  }
  ((u32*)out)[(size_t)row*384 + h*64 + lane] = (u32)f2bf(accx) | ((u32)f2bf(accy) << 16);
}

extern "C" void kernel_launch(void* const* d_in, const int* in_sizes, int n_in,
                              void* d_out, int out_size, void* d_ws, size_t ws_size,
                              hipStream_t stream) {
  const void* x       = d_in[0];
  const void* refp    = d_in[1];
  const void* feat    = d_in[2];
  const void* qn_w    = d_in[5];
  const void* qn_b    = d_in[6];
  const void* fn_w    = d_in[7];
  const void* fn_b    = d_in[8];
  const void* gamma   = d_in[9];
  const void* w_value = d_in[10];
  const void* b_value = d_in[11];
  const void* w_off   = d_in[12];
  const void* b_off   = d_in[13];
  const void* w_attn  = d_in[14];
  const void* b_attn  = d_in[15];
  const void* w_out   = d_in[16];
  const void* b_out   = d_in[17];

  char* p = (char*)d_ws;
  const size_t act = (size_t)NROWS * CDIM * 2;       // 12.58 MB
  u16* q_bf   = (u16*)p; p += act;
  u16* f_bf   = (u16*)p; p += act;
  u16* val_bf = (u16*)p; p += act;
  u16* wvT    = (u16*)p; p += (size_t)CDIM*CDIM*2;
  u16* woT    = (u16*)p; p += (size_t)CDIM*CDIM*2;
  u16* woaT   = (u16*)p; p += (size_t)128*CDIM*2;
  float* offawp = (float*)p; p += (size_t)2*NROWS*72*4;
  int* dflag  = (int*)p; p += 256;
  u16* samp_bf = q_bf;   // q_bf dead after gemm_bt<1>; reuse

  detect_kernel<<<dim3(1), 256, 0, stream>>>((const u16*)x, dflag);
  transpose_wt<<<dim3(24,24,2), 256, 0, stream>>>(w_value, w_out, wvT, woT, dflag);
  build_woffaw<<<dim3(384), 256, 0, stream>>>(w_off, w_attn, woaT, dflag);
  ln_kernel<<<dim3(16384), 192, 0, stream>>>(x, feat, qn_w, qn_b, fn_w, fn_b, q_bf, f_bf, dflag);
  gemm_bt<0><<<dim3(64,12,1), 256, 0, stream>>>(f_bf, wvT, val_bf, b_value, nullptr, nullptr, nullptr, dflag);
  gemm_bt<1><<<dim3(64,2,2),  256, 0, stream>>>(q_bf, woaT, offawp, b_off, b_attn, nullptr, nullptr, dflag);
  sample_kernel<<<dim3(12288), 256, 0, stream>>>(val_bf, offawp, refp, samp_bf, dflag);
  gemm_bt<2><<<dim3(64,12,1), 256, 0, stream>>>(samp_bf, woT, d_out, b_out, nullptr, x, gamma, dflag);
}

// Round 7
// 241.270 us; speedup vs baseline: 1.1045x; 1.0183x over previous
//
#include <hip/hip_runtime.h>
#include <cstdint>
#include <cstddef>

typedef unsigned short u16;
typedef unsigned int u32;
typedef __bf16 bf16x8 __attribute__((ext_vector_type(8)));
typedef float f32x4 __attribute__((ext_vector_type(4)));

static constexpr int CDIM = 768;
static constexpr int NROWS = 8192;   // B*Lq == B*H*W
static constexpr int ASTR = 72;      // padded LDS row stride (u16) for A/B tiles

__device__ __forceinline__ u16 f2bf(float f) {
  union { float f; u32 u; } v; v.f = f;
  return (u16)((v.u + 0x7fffu + ((v.u >> 16) & 1u)) >> 16);   // RNE
}
__device__ __forceinline__ float bf2f(u16 h) {
  union { u32 u; float f; } v; v.u = ((u32)h) << 16;
  return v.f;
}
// Load element i of an external tensor whose dtype is runtime-detected: F=1 f32, F=0 bf16.
__device__ __forceinline__ float ldf(const void* p, size_t i, int F) {
  return F ? ((const float*)p)[i] : bf2f(((const u16*)p)[i]);
}

// ---------------- dtype detection ----------------
__global__ __launch_bounds__(256) void detect_kernel(const u16* __restrict__ x, int* __restrict__ flag) {
  int t = threadIdx.x;
  int cnt = 0;
  for (int i = t; i < 16384; i += 256) {
    u16 v = x[i];
    if ((v & 0x7F80u) == 0x7F80u) cnt++;   // bf16 NaN/Inf pattern
  }
  #pragma unroll
  for (int m = 32; m >= 1; m >>= 1) cnt += __shfl_xor(cnt, m, 64);
  __shared__ int r[4];
  if ((t & 63) == 0) r[t >> 6] = cnt;
  __syncthreads();
  if (t == 0) flag[0] = (r[0] + r[1] + r[2] + r[3] > 4) ? 1 : 0;   // 1 = f32 inputs
}

// ---------------- fused LayerNorm, vectorized: 192 threads, one row/block ----------------
__global__ __launch_bounds__(192) void ln_kernel(
    const void* __restrict__ x, const void* __restrict__ feat,
    const void* __restrict__ qw, const void* __restrict__ qb,
    const void* __restrict__ fw, const void* __restrict__ fb,
    u16* __restrict__ qout, u16* __restrict__ fout, const int* __restrict__ flagp) {
  const int F = *flagp;
  int row = blockIdx.x;   // 0..16383
  const void *src, *w, *b; u16* dst; size_t base;
  if (row < NROWS) { src = x; base = (size_t)row*CDIM; w = qw; b = qb; dst = qout + base; }
  else { int r2 = row - NROWS; src = feat; base = (size_t)r2*CDIM; w = fw; b = fb; dst = fout + (size_t)r2*CDIM; }
  int t = threadIdx.x;     // 0..191, covers 4 elems each
  float v[4];
  if (F) {
    float4 q = ((const float4*)((const float*)src + base))[t];
    v[0]=q.x; v[1]=q.y; v[2]=q.z; v[3]=q.w;
  } else {
    const u16* sp = (const u16*)src + base + t*4;
    v[0]=bf2f(sp[0]); v[1]=bf2f(sp[1]); v[2]=bf2f(sp[2]); v[3]=bf2f(sp[3]);
  }
  float s = v[0]+v[1]+v[2]+v[3];
  float sq = v[0]*v[0]+v[1]*v[1]+v[2]*v[2]+v[3]*v[3];
  #pragma unroll
  for (int m = 32; m >= 1; m >>= 1) { s += __shfl_xor(s, m, 64); sq += __shfl_xor(sq, m, 64); }
  __shared__ float red[6];
  int lane = t & 63, wv = t >> 6;
  if (lane == 0) { red[wv] = s; red[wv+3] = sq; }
  __syncthreads();
  s  = red[0]+red[1]+red[2];
  sq = red[3]+red[4]+red[5];
  float mean = s * (1.f/768.f);
  float var  = fmaxf(sq * (1.f/768.f) - mean*mean, 0.f);
  float inv  = rsqrtf(var + 1e-6f);
  u16 o[4];
  #pragma unroll
  for (int k = 0; k < 4; ++k) {
    float wk = ldf(w, t*4+k, F), bk = ldf(b, t*4+k, F);
    o[k] = f2bf((v[k]-mean)*inv*wk + bk);
  }
  *(ushort4*)(dst + t*4) = make_ushort4(o[0], o[1], o[2], o[3]);
}

// ---------------- transpose weights [K=768][N=768] -> [N][K], to bf16 ----------------
__global__ __launch_bounds__(256) void transpose_wt(
    const void* __restrict__ wv_, const void* __restrict__ wo_,
    u16* __restrict__ wvT, u16* __restrict__ woT, const int* __restrict__ flagp) {
  const int F = *flagp;
  __shared__ u16 tile[32][33];
  const void* in = blockIdx.z ? wo_ : wv_;
  u16* out       = blockIdx.z ? woT : wvT;
  int bn = blockIdx.x * 32;
  int bk = blockIdx.y * 32;
  int tx = threadIdx.x & 31, ty = threadIdx.x >> 5;
  #pragma unroll
  for (int i = ty; i < 32; i += 8)
    tile[i][tx] = F ? f2bf(((const float*)in)[(size_t)(bk+i)*CDIM + bn + tx])
                    : ((const u16*)in)[(size_t)(bk+i)*CDIM + bn + tx];
  __syncthreads();
  #pragma unroll
  for (int i = ty; i < 32; i += 8)
    out[(size_t)(bn+i)*CDIM + bk + tx] = tile[tx][i];
}

// ---------------- build padded [128][768] B^T for [w_off | w_attn | 0], bf16 ----------------
__global__ __launch_bounds__(256) void build_woffaw(
    const void* __restrict__ woff, const void* __restrict__ wattn, u16* __restrict__ outT,
    const int* __restrict__ flagp) {
  const int F = *flagp;
  int idx = blockIdx.x * 256 + threadIdx.x;
  if (idx >= 128 * CDIM) return;
  int n = idx / CDIM, k = idx - n*CDIM;
  float v = 0.f;
  if (n < 48)      v = ldf(woff, (size_t)k*48 + n, F);
  else if (n < 72) v = ldf(wattn, (size_t)k*24 + (n-48), F);
  outT[idx] = f2bf(v);
}

// ---------------- MFMA GEMM: C[M,N] = A[M,768]*Bt[N,768]^T, tile 128x64, BK=64 ----------------
// Round-4 structure (plain vectorized staging, padded LDS) — measured faster than async BK=32.
// grid (M/128, N/64, KS).  EPI 0: bf16 C+bias.  EPI 1: f32 K-partials [z][M][72], bias in z==0.
// EPI 2: out = x + gamma*(C + bias), dtype per flag.
template<int EPI>
__global__ __launch_bounds__(256) void gemm_bt(
    const u16* __restrict__ A, const u16* __restrict__ Bt, void* __restrict__ Cout,
    const void* __restrict__ bias0, const void* __restrict__ bias1,
    const void* __restrict__ xres, const void* __restrict__ gammap,
    const int* __restrict__ flagp) {
  const int F = *flagp;
  __shared__ __align__(16) u16 smem[(128+64)*ASTR];   // 27.6 KB; Cs aliases As region
  u16* As = smem;              // [128][ASTR]
  u16* Bs = smem + 128*ASTR;   // [64][ASTR]
  u16* Cs = smem;              // [128][64] epilogue staging
  const int m0 = blockIdx.x * 128;
  const int n0 = blockIdx.y * 64;
  const int t = threadIdx.x, lane = t & 63, wv = t >> 6;
  const int wm = wv & 1, wn = wv >> 1;
  const int kChunk = CDIM / gridDim.z;
  const int kbase = blockIdx.z * kChunk;
  const int lr = lane >> 3;          // staging row-in-segment
  const int lc = (lane & 7) * 8;     // staging col (u16)
  f32x4 acc[4][2] = {};

  for (int kk = 0; kk < kChunk; kk += 64) {
    const int k0 = kbase + kk;
    #pragma unroll
    for (int j = 0; j < 4; ++j) {                  // A: 16 segments of 8 rows
      int row = (wv*4 + j)*8 + lr;
      *(bf16x8*)(As + row*ASTR + lc) = *(const bf16x8*)(A + (size_t)(m0+row)*CDIM + k0 + lc);
    }
    #pragma unroll
    for (int j = 0; j < 2; ++j) {                  // B: 8 segments of 8 rows
      int row = (wv*2 + j)*8 + lr;
      *(bf16x8*)(Bs + row*ASTR + lc) = *(const bf16x8*)(Bt + (size_t)(n0+row)*CDIM + k0 + lc);
    }
    __syncthreads();
    #pragma unroll
    for (int u = 0; u < 2; ++u) {
      bf16x8 af[4], bfr[2];
      const int kc = u*32 + (lane >> 4)*8;
      #pragma unroll
      for (int i = 0; i < 4; ++i)
        af[i]  = *(const bf16x8*)(As + (wm*64 + i*16 + (lane & 15))*ASTR + kc);
      #pragma unroll
      for (int j = 0; j < 2; ++j)
        bfr[j] = *(const bf16x8*)(Bs + (wn*32 + j*16 + (lane & 15))*ASTR + kc);
      #pragma unroll
      for (int i = 0; i < 4; ++i)
        #pragma unroll
        for (int j = 0; j < 2; ++j)
          acc[i][j] = __builtin_amdgcn_mfma_f32_16x16x32_bf16(af[i], bfr[j], acc[i][j], 0, 0, 0);
    }
    __syncthreads();
  }

  const int r0 = (lane >> 4) * 4;    // C/D: col=lane&15, row=(lane>>4)*4+reg  [m89/m91]
  const int c  = lane & 15;

  if (EPI == 1) {                    // scattered f32 partial stores (only 72 cols live)
    float* op = (float*)Cout + (size_t)blockIdx.z * NROWS * 72;
    #pragma unroll
    for (int i = 0; i < 4; ++i)
      #pragma unroll
      for (int j = 0; j < 2; ++j) {
        int col = n0 + wn*32 + j*16 + c;
        if (col < 72) {
          float bb = 0.f;
          if (blockIdx.z == 0) bb = (col < 48) ? ldf(bias0, col, F) : ldf(bias1, col-48, F);
          #pragma unroll
          for (int r = 0; r < 4; ++r)
            op[(size_t)(m0 + wm*64 + i*16 + r0 + r)*72 + col] = acc[i][j][r] + bb;
        }
      }
    return;
  }

  // stage (acc + bias) as bf16 into Cs, then coalesced 16B stores
  #pragma unroll
  for (int i = 0; i < 4; ++i)
    #pragma unroll
    for (int j = 0; j < 2; ++j) {
      int col = wn*32 + j*16 + c;
      float bb = ldf(bias0, n0 + col, F);
      #pragma unroll
      for (int r = 0; r < 4; ++r)
        Cs[(wm*64 + i*16 + r0 + r)*64 + col] = f2bf(acc[i][j][r] + bb);
    }
  __syncthreads();
  #pragma unroll
  for (int it = 0; it < 4; ++it) {
    int idx = it*256 + t;            // 0..1023, 16B each -> 128x64 u16 tile
    int row = idx >> 3, colb = (idx & 7) * 8;
    size_t gbase = (size_t)(m0 + row)*CDIM + n0 + colb;
    const u16* cp = Cs + row*64 + colb;
    if (EPI == 0) {
      *(bf16x8*)((u16*)Cout + gbase) = *(const bf16x8*)cp;
    } else {                          // EPI 2
      if (F) {
        const float* xp = (const float*)xres + gbase;
        const float* gp = (const float*)gammap + n0 + colb;
        float4 x0 = *(const float4*)xp,      x1 = *(const float4*)(xp + 4);
        float4 g0 = *(const float4*)gp,      g1 = *(const float4*)(gp + 4);
        float4 o0, o1;
        o0.x = x0.x + g0.x*bf2f(cp[0]); o0.y = x0.y + g0.y*bf2f(cp[1]);
        o0.z = x0.z + g0.z*bf2f(cp[2]); o0.w = x0.w + g0.w*bf2f(cp[3]);
        o1.x = x1.x + g1.x*bf2f(cp[4]); o1.y = x1.y + g1.y*bf2f(cp[5]);
        o1.z = x1.z + g1.z*bf2f(cp[6]); o1.w = x1.w + g1.w*bf2f(cp[7]);
        *(float4*)((float*)Cout + gbase)     = o0;
        *(float4*)((float*)Cout + gbase + 4) = o1;
      } else {
        const u16* xp = (const u16*)xres + gbase;
        const u16* gp = (const u16*)gammap + n0 + colb;
        u16 ov[8];
        #pragma unroll
        for (int k = 0; k < 8; ++k)
          ov[k] = f2bf(bf2f(xp[k]) + bf2f(gp[k]) * bf2f(cp[k]));
        *(bf16x8*)((u16*)Cout + gbase) = *(const bf16x8*)ov;
      }
    }
  }
}

// ---------------- deformable sampling: wave handles 2 heads of one row, 32-load burst ----------------
__global__ __launch_bounds__(256) void sample_kernel(
    const u16* __restrict__ value,   // [B*4096][768] bf16, col = h*128+d
    const float* __restrict__ offawp,// [2][8192][72] f32 K-partials
    const void* __restrict__ refp,   // [8192][2] external dtype
    u16* __restrict__ out, const int* __restrict__ flagp) {
  const int F = *flagp;
  const int wq   = blockIdx.x * 4 + (threadIdx.x >> 6);  // 0..24575
  const int lane = threadIdx.x & 63;
  const int row  = wq / 3;            // 0..8191 (shared by both tasks)
  const int h0   = (wq % 3) * 2;      // 0,2,4
  const int b    = row >> 12;
  const float* p0 = offawp + (size_t)row*72;
  const float* p1 = p0 + (size_t)NROWS*72;
  float rx = ldf(refp, (size_t)row*2,   F) * 64.f - 0.5f;
  float ry = ldf(refp, (size_t)row*2+1, F) * 64.f - 0.5f;

  float wts[2][16]; int offs[2][16];
  #pragma unroll
  for (int s = 0; s < 2; ++s) {
    const int h = h0 + s;
    float ob[8], aw4[4];
    #pragma unroll
    for (int k = 0; k < 8; ++k) ob[k] = p0[h*8+k] + p1[h*8+k];
    #pragma unroll
    for (int k = 0; k < 4; ++k) aw4[k] = p0[48+h*4+k] + p1[48+h*4+k];
    float mx = fmaxf(fmaxf(aw4[0],aw4[1]), fmaxf(aw4[2],aw4[3]));
    float e0 = __expf(aw4[0]-mx), e1 = __expf(aw4[1]-mx), e2 = __expf(aw4[2]-mx), e3 = __expf(aw4[3]-mx);
    float rs = 1.f / (e0+e1+e2+e3);
    float awt[4] = {e0*rs, e1*rs, e2*rs, e3*rs};
    #pragma unroll
    for (int p = 0; p < 4; ++p) {
      float px = rx + ob[p*2];
      float py = ry + ob[p*2+1];
      float x0f = floorf(px), y0f = floorf(py);
      float fx = px - x0f, fy = py - y0f;
      int x0 = (int)x0f, y0 = (int)y0f;
      #pragma unroll
      for (int dy = 0; dy < 2; ++dy)
        #pragma unroll
        for (int dx = 0; dx < 2; ++dx) {
          int yi = y0 + dy, xi = x0 + dx;
          bool valid = (yi >= 0) & (yi < 64) & (xi >= 0) & (xi < 64);
          float wt = (dy ? fy : 1.f-fy) * (dx ? fx : 1.f-fx) * awt[p];
          wts[s][p*4+dy*2+dx] = valid ? wt : 0.f;
          int yc = min(max(yi, 0), 63), xc = min(max(xi, 0), 63);
          offs[s][p*4+dy*2+dx] = (yc*64 + xc) * 384;
        }
    }
  }
  const u32* vbase = (const u32*)value + (size_t)b*4096*384 + h0*64 + lane;
  u32 vals[2][16];
  #pragma unroll
  for (int s = 0; s < 2; ++s)
    #pragma unroll
    for (int i = 0; i < 16; ++i)
      vals[s][i] = (vbase + s*64)[offs[s][i]];   // 32 loads in flight
  #pragma unroll
  for (int s = 0; s < 2; ++s) {
    float accx = 0.f, accy = 0.f;
    #pragma unroll
    for (int i = 0; i < 16; ++i) {
      accx += wts[s][i] * bf2f((u16)(vals[s][i] & 0xffffu));
      accy += wts[s][i] * bf2f((u16)(vals[s][i] >> 16));
    }
    ((u32*)out)[(size_t)row*384 + (h0+s)*64 + lane] = (u32)f2bf(accx) | ((u32)f2bf(accy) << 16);
  }
}

extern "C" void kernel_launch(void* const* d_in, const int* in_sizes, int n_in,
                              void* d_out, int out_size, void* d_ws, size_t ws_size,
                              hipStream_t stream) {
  const void* x       = d_in[0];
  const void* refp    = d_in[1];
  const void* feat    = d_in[2];
  const void* qn_w    = d_in[5];
  const void* qn_b    = d_in[6];
  const void* fn_w    = d_in[7];
  const void* fn_b    = d_in[8];
  const void* gamma   = d_in[9];
  const void* w_value = d_in[10];
  const void* b_value = d_in[11];
  const void* w_off   = d_in[12];
  const void* b_off   = d_in[13];
  const void* w_attn  = d_in[14];
  const void* b_attn  = d_in[15];
  const void* w_out   = d_in[16];
  const void* b_out   = d_in[17];

  char* p = (char*)d_ws;
  const size_t act = (size_t)NROWS * CDIM * 2;       // 12.58 MB
  u16* q_bf   = (u16*)p; p += act;
  u16* f_bf   = (u16*)p; p += act;
  u16* val_bf = (u16*)p; p += act;
  u16* wvT    = (u16*)p; p += (size_t)CDIM*CDIM*2;
  u16* woT    = (u16*)p; p += (size_t)CDIM*CDIM*2;
  u16* woaT   = (u16*)p; p += (size_t)128*CDIM*2;
  float* offawp = (float*)p; p += (size_t)2*NROWS*72*4;
  int* dflag  = (int*)p; p += 256;
  u16* samp_bf = q_bf;   // q_bf dead after gemm_bt<1>; reuse

  detect_kernel<<<dim3(1), 256, 0, stream>>>((const u16*)x, dflag);
  transpose_wt<<<dim3(24,24,2), 256, 0, stream>>>(w_value, w_out, wvT, woT, dflag);
  build_woffaw<<<dim3(384), 256, 0, stream>>>(w_off, w_attn, woaT, dflag);
  ln_kernel<<<dim3(16384), 192, 0, stream>>>(x, feat, qn_w, qn_b, fn_w, fn_b, q_bf, f_bf, dflag);
  gemm_bt<0><<<dim3(64,12,1), 256, 0, stream>>>(f_bf, wvT, val_bf, b_value, nullptr, nullptr, nullptr, dflag);
  gemm_bt<1><<<dim3(64,2,2),  256, 0, stream>>>(q_bf, woaT, offawp, b_off, b_attn, nullptr, nullptr, dflag);
  sample_kernel<<<dim3(6144), 256, 0, stream>>>(val_bf, offawp, refp, samp_bf, dflag);
  gemm_bt<2><<<dim3(64,12,1), 256, 0, stream>>>(samp_bf, woT, d_out, b_out, nullptr, x, gamma, dflag);
}

// Round 8
// 232.833 us; speedup vs baseline: 1.1445x; 1.0362x over previous
//
#include <hip/hip_runtime.h>
#include <cstdint>
#include <cstddef>

#define GLOBAL_AS __attribute__((address_space(1)))
#define LDS_AS __attribute__((address_space(3)))

typedef unsigned short u16;
typedef unsigned int u32;
typedef __bf16 bf16x8 __attribute__((ext_vector_type(8)));
typedef float f32x4 __attribute__((ext_vector_type(4)));

static constexpr int CDIM = 768;
static constexpr int NROWS = 8192;   // B*Lq == B*H*W
static constexpr int KS1 = 4;        // split-K for the off/attn GEMM

__device__ __forceinline__ u16 f2bf(float f) {
  union { float f; u32 u; } v; v.f = f;
  return (u16)((v.u + 0x7fffu + ((v.u >> 16) & 1u)) >> 16);   // RNE
}
__device__ __forceinline__ float bf2f(u16 h) {
  union { u32 u; float f; } v; v.u = ((u32)h) << 16;
  return v.f;
}
// Load element i of an external tensor whose dtype is runtime-detected: F=1 f32, F=0 bf16.
__device__ __forceinline__ float ldf(const void* p, size_t i, int F) {
  return F ? ((const float*)p)[i] : bf2f(((const u16*)p)[i]);
}
// async 16B/lane global->LDS; LDS dest = wave-uniform base + lane*16 [m97]
__device__ __forceinline__ void load_lds16(const u16* g, u16* l) {
  __builtin_amdgcn_global_load_lds((const GLOBAL_AS u32*)g, (LDS_AS u32*)l, 16, 0, 0);
}

// ---------------- dtype detection ----------------
__global__ __launch_bounds__(256) void detect_kernel(const u16* __restrict__ x, int* __restrict__ flag) {
  int t = threadIdx.x;
  int cnt = 0;
  for (int i = t; i < 16384; i += 256) {
    u16 v = x[i];
    if ((v & 0x7F80u) == 0x7F80u) cnt++;   // bf16 NaN/Inf pattern
  }
  #pragma unroll
  for (int m = 32; m >= 1; m >>= 1) cnt += __shfl_xor(cnt, m, 64);
  __shared__ int r[4];
  if ((t & 63) == 0) r[t >> 6] = cnt;
  __syncthreads();
  if (t == 0) flag[0] = (r[0] + r[1] + r[2] + r[3] > 4) ? 1 : 0;   // 1 = f32 inputs
}

// ---------------- fused LayerNorm, vectorized: 192 threads, one row/block ----------------
__global__ __launch_bounds__(192) void ln_kernel(
    const void* __restrict__ x, const void* __restrict__ feat,
    const void* __restrict__ qw, const void* __restrict__ qb,
    const void* __restrict__ fw, const void* __restrict__ fb,
    u16* __restrict__ qout, u16* __restrict__ fout, const int* __restrict__ flagp) {
  const int F = *flagp;
  int row = blockIdx.x;   // 0..16383
  const void *src, *w, *b; u16* dst; size_t base;
  if (row < NROWS) { src = x; base = (size_t)row*CDIM; w = qw; b = qb; dst = qout + base; }
  else { int r2 = row - NROWS; src = feat; base = (size_t)r2*CDIM; w = fw; b = fb; dst = fout + (size_t)r2*CDIM; }
  int t = threadIdx.x;     // 0..191, covers 4 elems each
  float v[4];
  if (F) {
    float4 q = ((const float4*)((const float*)src + base))[t];
    v[0]=q.x; v[1]=q.y; v[2]=q.z; v[3]=q.w;
  } else {
    const u16* sp = (const u16*)src + base + t*4;
    v[0]=bf2f(sp[0]); v[1]=bf2f(sp[1]); v[2]=bf2f(sp[2]); v[3]=bf2f(sp[3]);
  }
  float s = v[0]+v[1]+v[2]+v[3];
  float sq = v[0]*v[0]+v[1]*v[1]+v[2]*v[2]+v[3]*v[3];
  #pragma unroll
  for (int m = 32; m >= 1; m >>= 1) { s += __shfl_xor(s, m, 64); sq += __shfl_xor(sq, m, 64); }
  __shared__ float red[6];
  int lane = t & 63, wv = t >> 6;
  if (lane == 0) { red[wv] = s; red[wv+3] = sq; }
  __syncthreads();
  s  = red[0]+red[1]+red[2];
  sq = red[3]+red[4]+red[5];
  float mean = s * (1.f/768.f);
  float var  = fmaxf(sq * (1.f/768.f) - mean*mean, 0.f);
  float inv  = rsqrtf(var + 1e-6f);
  u16 o[4];
  #pragma unroll
  for (int k = 0; k < 4; ++k) {
    float wk = ldf(w, t*4+k, F), bk = ldf(b, t*4+k, F);
    o[k] = f2bf((v[k]-mean)*inv*wk + bk);
  }
  *(ushort4*)(dst + t*4) = make_ushort4(o[0], o[1], o[2], o[3]);
}

// ---------------- prep: z<2 transpose w_value/w_out [K][N]->[N][K]; z==2 build [128][768] woaT ----------------
__global__ __launch_bounds__(256) void prep_kernel(
    const void* __restrict__ wv_, const void* __restrict__ wo_,
    const void* __restrict__ woff, const void* __restrict__ wattn,
    u16* __restrict__ wvT, u16* __restrict__ woT, u16* __restrict__ woaT,
    const int* __restrict__ flagp) {
  const int F = *flagp;
  if (blockIdx.z == 2) {
    int idx = (blockIdx.y * 24 + blockIdx.x) * 256 + threadIdx.x;
    if (idx >= 128 * CDIM) return;
    int n = idx / CDIM, k = idx - n*CDIM;
    float v = 0.f;
    if (n < 48)      v = ldf(woff, (size_t)k*48 + n, F);
    else if (n < 72) v = ldf(wattn, (size_t)k*24 + (n-48), F);
    woaT[idx] = f2bf(v);
    return;
  }
  __shared__ u16 tile[32][33];
  const void* in = blockIdx.z ? wo_ : wv_;
  u16* out       = blockIdx.z ? woT : wvT;
  int bn = blockIdx.x * 32;
  int bk = blockIdx.y * 32;
  int tx = threadIdx.x & 31, ty = threadIdx.x >> 5;
  #pragma unroll
  for (int i = ty; i < 32; i += 8)
    tile[i][tx] = F ? f2bf(((const float*)in)[(size_t)(bk+i)*CDIM + bn + tx])
                    : ((const u16*)in)[(size_t)(bk+i)*CDIM + bn + tx];
  __syncthreads();
  #pragma unroll
  for (int i = ty; i < 32; i += 8)
    out[(size_t)(bn+i)*CDIM + bk + tx] = tile[tx][i];
}

// ---------------- MFMA GEMM: C[M,N] = A[M,768]*Bt[N,768]^T, tile 128x64, BK=64 ----------------
// Async global_load_lds staging into dual unpadded [row][32] panels (m97 layout per panel).
// grid (M/128, N/64, KS).  EPI 0: bf16 C+bias.  EPI 1: f32 K-partials [z][M][72], bias in z==0.
// EPI 2: out = x + gamma*(C + bias), dtype per flag.
template<int EPI>
__global__ __launch_bounds__(256) void gemm_bt(
    const u16* __restrict__ A, const u16* __restrict__ Bt, void* __restrict__ Cout,
    const void* __restrict__ bias0, const void* __restrict__ bias1,
    const void* __restrict__ xres, const void* __restrict__ gammap,
    const int* __restrict__ flagp) {
  const int F = *flagp;
  __shared__ __align__(16) u16 smem[12288];  // 24 KB: As 2x4096 | Bs 2x2048; Cs[128][64] aliases
  u16* As = smem;            // panel p at As + p*4096, layout [row][32]
  u16* Bs = smem + 8192;     // panel p at Bs + p*2048
  u16* Cs = smem;            // 8192 u16 epilogue staging
  const int m0 = blockIdx.x * 128;
  const int n0 = blockIdx.y * 64;
  const int t = threadIdx.x, lane = t & 63, wv = t >> 6;
  const int wm = wv & 1, wn = wv >> 1;
  const int kChunk = CDIM / gridDim.z;
  const int kbase = blockIdx.z * kChunk;
  const int lrow = lane >> 2;        // 0..15 row within 16-row segment
  const int lcol = (lane & 3) * 8;   // u16 col within 32-wide panel row
  f32x4 acc[4][2] = {};

  for (int k0 = kbase; k0 < kbase + kChunk; k0 += 64) {
    #pragma unroll
    for (int j = 0; j < 4; ++j) {                  // A: 16 1KB segments (2 panels x 8)
      int g = wv*4 + j;                            // 0..15
      int p = g >> 3, s = g & 7;
      load_lds16(A + (size_t)(m0 + s*16 + lrow)*CDIM + k0 + p*32 + lcol,
                 As + p*4096 + s*512);
    }
    #pragma unroll
    for (int j = 0; j < 2; ++j) {                  // B: 8 segments (2 panels x 4)
      int g = wv*2 + j;                            // 0..7
      int p = g >> 2, s = g & 3;
      load_lds16(Bt + (size_t)(n0 + s*16 + lrow)*CDIM + k0 + p*32 + lcol,
                 Bs + p*2048 + s*512);
    }
    __syncthreads();
    #pragma unroll
    for (int u = 0; u < 2; ++u) {
      bf16x8 af[4], bfr[2];
      const int kc = (lane >> 4) * 8;
      #pragma unroll
      for (int i = 0; i < 4; ++i)
        af[i]  = *(const bf16x8*)(As + u*4096 + (wm*64 + i*16 + (lane & 15))*32 + kc);
      #pragma unroll
      for (int j = 0; j < 2; ++j)
        bfr[j] = *(const bf16x8*)(Bs + u*2048 + (wn*32 + j*16 + (lane & 15))*32 + kc);
      #pragma unroll
      for (int i = 0; i < 4; ++i)
        #pragma unroll
        for (int j = 0; j < 2; ++j)
          acc[i][j] = __builtin_amdgcn_mfma_f32_16x16x32_bf16(af[i], bfr[j], acc[i][j], 0, 0, 0);
    }
    __syncthreads();
  }

  const int r0 = (lane >> 4) * 4;    // C/D: col=lane&15, row=(lane>>4)*4+reg  [m89/m91]
  const int c  = lane & 15;

  if (EPI == 1) {                    // scattered f32 partial stores (only 72 cols live)
    float* op = (float*)Cout + (size_t)blockIdx.z * NROWS * 72;
    #pragma unroll
    for (int i = 0; i < 4; ++i)
      #pragma unroll
      for (int j = 0; j < 2; ++j) {
        int col = n0 + wn*32 + j*16 + c;
        if (col < 72) {
          float bb = 0.f;
          if (blockIdx.z == 0) bb = (col < 48) ? ldf(bias0, col, F) : ldf(bias1, col-48, F);
          #pragma unroll
          for (int r = 0; r < 4; ++r)
            op[(size_t)(m0 + wm*64 + i*16 + r0 + r)*72 + col] = acc[i][j][r] + bb;
        }
      }
    return;
  }

  // stage (acc + bias) as bf16 into Cs, then coalesced 16B stores
  #pragma unroll
  for (int i = 0; i < 4; ++i)
    #pragma unroll
    for (int j = 0; j < 2; ++j) {
      int col = wn*32 + j*16 + c;
      float bb = ldf(bias0, n0 + col, F);
      #pragma unroll
      for (int r = 0; r < 4; ++r)
        Cs[(wm*64 + i*16 + r0 + r)*64 + col] = f2bf(acc[i][j][r] + bb);
    }
  __syncthreads();
  #pragma unroll
  for (int it = 0; it < 4; ++it) {
    int idx = it*256 + t;            // 0..1023, 16B each -> 128x64 u16 tile
    int row = idx >> 3, colb = (idx & 7) * 8;
    size_t gbase = (size_t)(m0 + row)*CDIM + n0 + colb;
    const u16* cp = Cs + row*64 + colb;
    if (EPI == 0) {
      *(bf16x8*)((u16*)Cout + gbase) = *(const bf16x8*)cp;
    } else {                          // EPI 2
      if (F) {
        const float* xp = (const float*)xres + gbase;
        const float* gp = (const float*)gammap + n0 + colb;
        float4 x0 = *(const float4*)xp,      x1 = *(const float4*)(xp + 4);
        float4 g0 = *(const float4*)gp,      g1 = *(const float4*)(gp + 4);
        float4 o0, o1;
        o0.x = x0.x + g0.x*bf2f(cp[0]); o0.y = x0.y + g0.y*bf2f(cp[1]);
        o0.z = x0.z + g0.z*bf2f(cp[2]); o0.w = x0.w + g0.w*bf2f(cp[3]);
        o1.x = x1.x + g1.x*bf2f(cp[4]); o1.y = x1.y + g1.y*bf2f(cp[5]);
        o1.z = x1.z + g1.z*bf2f(cp[6]); o1.w = x1.w + g1.w*bf2f(cp[7]);
        *(float4*)((float*)Cout + gbase)     = o0;
        *(float4*)((float*)Cout + gbase + 4) = o1;
      } else {
        const u16* xp = (const u16*)xres + gbase;
        const u16* gp = (const u16*)gammap + n0 + colb;
        u16 ov[8];
        #pragma unroll
        for (int k = 0; k < 8; ++k)
          ov[k] = f2bf(bf2f(xp[k]) + bf2f(gp[k]) * bf2f(cp[k]));
        *(bf16x8*)((u16*)Cout + gbase) = *(const bf16x8*)ov;
      }
    }
  }
}

// ---------------- deformable sampling: wave handles 2 heads of one row, 32-load burst ----------------
__global__ __launch_bounds__(256) void sample_kernel(
    const u16* __restrict__ value,   // [B*4096][768] bf16, col = h*128+d
    const float* __restrict__ offawp,// [KS1][8192][72] f32 K-partials
    const void* __restrict__ refp,   // [8192][2] external dtype
    u16* __restrict__ out, const int* __restrict__ flagp) {
  const int F = *flagp;
  const int wq   = blockIdx.x * 4 + (threadIdx.x >> 6);  // 0..24575
  const int lane = threadIdx.x & 63;
  const int row  = wq / 3;            // 0..8191 (shared by both tasks)
  const int h0   = (wq % 3) * 2;      // 0,2,4
  const int b    = row >> 12;
  const float* pr = offawp + (size_t)row*72;
  float rx = ldf(refp, (size_t)row*2,   F) * 64.f - 0.5f;
  float ry = ldf(refp, (size_t)row*2+1, F) * 64.f - 0.5f;

  float wts[2][16]; int offs[2][16];
  #pragma unroll
  for (int s = 0; s < 2; ++s) {
    const int h = h0 + s;
    float ob[8], aw4[4];
    #pragma unroll
    for (int k = 0; k < 8; ++k) {
      float v = 0.f;
      #pragma unroll
      for (int z = 0; z < KS1; ++z) v += pr[(size_t)z*NROWS*72 + h*8 + k];
      ob[k] = v;
    }
    #pragma unroll
    for (int k = 0; k < 4; ++k) {
      float v = 0.f;
      #pragma unroll
      for (int z = 0; z < KS1; ++z) v += pr[(size_t)z*NROWS*72 + 48 + h*4 + k];
      aw4[k] = v;
    }
    float mx = fmaxf(fmaxf(aw4[0],aw4[1]), fmaxf(aw4[2],aw4[3]));
    float e0 = __expf(aw4[0]-mx), e1 = __expf(aw4[1]-mx), e2 = __expf(aw4[2]-mx), e3 = __expf(aw4[3]-mx);
    float rs = 1.f / (e0+e1+e2+e3);
    float awt[4] = {e0*rs, e1*rs, e2*rs, e3*rs};
    #pragma unroll
    for (int p = 0; p < 4; ++p) {
      float px = rx + ob[p*2];
      float py = ry + ob[p*2+1];
      float x0f = floorf(px), y0f = floorf(py);
      float fx = px - x0f, fy = py - y0f;
      int x0 = (int)x0f, y0 = (int)y0f;
      #pragma unroll
      for (int dy = 0; dy < 2; ++dy)
        #pragma unroll
        for (int dx = 0; dx < 2; ++dx) {
          int yi = y0 + dy, xi = x0 + dx;
          bool valid = (yi >= 0) & (yi < 64) & (xi >= 0) & (xi < 64);
          float wt = (dy ? fy : 1.f-fy) * (dx ? fx : 1.f-fx) * awt[p];
          wts[s][p*4+dy*2+dx] = valid ? wt : 0.f;
          int yc = min(max(yi, 0), 63), xc = min(max(xi, 0), 63);
          offs[s][p*4+dy*2+dx] = (yc*64 + xc) * 384;
        }
    }
  }
  const u32* vbase = (const u32*)value + (size_t)b*4096*384 + h0*64 + lane;
  u32 vals[2][16];
  #pragma unroll
  for (int s = 0; s < 2; ++s)
    #pragma unroll
    for (int i = 0; i < 16; ++i)
      vals[s][i] = (vbase + s*64)[offs[s][i]];   // 32 loads in flight
  #pragma unroll
  for (int s = 0; s < 2; ++s) {
    float accx = 0.f, accy = 0.f;
    #pragma unroll
    for (int i = 0; i < 16; ++i) {
      accx += wts[s][i] * bf2f((u16)(vals[s][i] & 0xffffu));
      accy += wts[s][i] * bf2f((u16)(vals[s][i] >> 16));
    }
    ((u32*)out)[(size_t)row*384 + (h0+s)*64 + lane] = (u32)f2bf(accx) | ((u32)f2bf(accy) << 16);
  }
}

extern "C" void kernel_launch(void* const* d_in, const int* in_sizes, int n_in,
                              void* d_out, int out_size, void* d_ws, size_t ws_size,
                              hipStream_t stream) {
  const void* x       = d_in[0];
  const void* refp    = d_in[1];
  const void* feat    = d_in[2];
  const void* qn_w    = d_in[5];
  const void* qn_b    = d_in[6];
  const void* fn_w    = d_in[7];
  const void* fn_b    = d_in[8];
  const void* gamma   = d_in[9];
  const void* w_value = d_in[10];
  const void* b_value = d_in[11];
  const void* w_off   = d_in[12];
  const void* b_off   = d_in[13];
  const void* w_attn  = d_in[14];
  const void* b_attn  = d_in[15];
  const void* w_out   = d_in[16];
  const void* b_out   = d_in[17];

  char* p = (char*)d_ws;
  const size_t act = (size_t)NROWS * CDIM * 2;       // 12.58 MB
  u16* q_bf   = (u16*)p; p += act;
  u16* f_bf   = (u16*)p; p += act;
  u16* val_bf = (u16*)p; p += act;
  u16* wvT    = (u16*)p; p += (size_t)CDIM*CDIM*2;
  u16* woT    = (u16*)p; p += (size_t)CDIM*CDIM*2;
  u16* woaT   = (u16*)p; p += (size_t)128*CDIM*2;
  float* offawp = (float*)p; p += (size_t)KS1*NROWS*72*4;
  int* dflag  = (int*)p; p += 256;
  u16* samp_bf = q_bf;   // q_bf dead after gemm_bt<1>; reuse

  detect_kernel<<<dim3(1), 256, 0, stream>>>((const u16*)x, dflag);
  prep_kernel<<<dim3(24,24,3), 256, 0, stream>>>(w_value, w_out, w_off, w_attn, wvT, woT, woaT, dflag);
  ln_kernel<<<dim3(16384), 192, 0, stream>>>(x, feat, qn_w, qn_b, fn_w, fn_b, q_bf, f_bf, dflag);
  gemm_bt<0><<<dim3(64,12,1),   256, 0, stream>>>(f_bf, wvT, val_bf, b_value, nullptr, nullptr, nullptr, dflag);
  gemm_bt<1><<<dim3(64,2,KS1),  256, 0, stream>>>(q_bf, woaT, offawp, b_off, b_attn, nullptr, nullptr, dflag);
  sample_kernel<<<dim3(6144), 256, 0, stream>>>(val_bf, offawp, refp, samp_bf, dflag);
  gemm_bt<2><<<dim3(64,12,1),   256, 0, stream>>>(samp_bf, woT, d_out, b_out, nullptr, x, gamma, dflag);
}

// Round 9
// 199.599 us; speedup vs baseline: 1.3351x; 1.1665x over previous
//
#include <hip/hip_runtime.h>
#include <cstdint>
#include <cstddef>

#define GLOBAL_AS __attribute__((address_space(1)))
#define LDS_AS __attribute__((address_space(3)))

typedef unsigned short u16;
typedef unsigned int u32;
typedef __bf16 bf16x8 __attribute__((ext_vector_type(8)));
typedef float f32x4 __attribute__((ext_vector_type(4)));

static constexpr int CDIM = 768;
static constexpr int NROWS = 8192;   // B*Lq == B*H*W
static constexpr int KS1 = 4;        // split-K for the off/attn GEMM
// Inputs/outputs are f32 [measured: r1-r2 bf16-interpretation -> NaN; r3-r8 detect->f32 path passes]

__device__ __forceinline__ u16 f2bf(float f) {
  union { float f; u32 u; } v; v.f = f;
  return (u16)((v.u + 0x7fffu + ((v.u >> 16) & 1u)) >> 16);   // RNE
}
__device__ __forceinline__ float bf2f(u16 h) {
  union { u32 u; float f; } v; v.u = ((u32)h) << 16;
  return v.f;
}
// async 16B/lane global->LDS; LDS dest = wave-uniform base + lane*16 [m97]
__device__ __forceinline__ void load_lds16(const u16* g, u16* l) {
  __builtin_amdgcn_global_load_lds((const GLOBAL_AS u32*)g, (LDS_AS u32*)l, 16, 0, 0);
}

// ---------------- pre: LN rows (blocks 0..16383) + weight prep (blocks 16384..18111) ----------------
__global__ __launch_bounds__(192) void pre_kernel(
    const float* __restrict__ x, const float* __restrict__ feat,
    const float* __restrict__ qw, const float* __restrict__ qb,
    const float* __restrict__ fw, const float* __restrict__ fb,
    const float* __restrict__ wv_, const float* __restrict__ wo_,
    const float* __restrict__ woff, const float* __restrict__ wattn,
    u16* __restrict__ qout, u16* __restrict__ fout,
    u16* __restrict__ wvT, u16* __restrict__ woT, u16* __restrict__ woaT) {
  __shared__ __align__(8) char shbuf[32*33*2];
  const int bx = blockIdx.x;
  const int t = threadIdx.x;
  if (bx < 2*NROWS) {                     // ---- LayerNorm ----
    const float *src, *w, *b; u16* dst; size_t base;
    if (bx < NROWS) { src = x; base = (size_t)bx*CDIM; w = qw; b = qb; dst = qout + base; }
    else { int r2 = bx - NROWS; src = feat; base = (size_t)r2*CDIM; w = fw; b = fb; dst = fout + (size_t)r2*CDIM; }
    float4 q = ((const float4*)(src + base))[t];
    float v[4] = {q.x, q.y, q.z, q.w};
    float s = v[0]+v[1]+v[2]+v[3];
    float sq = v[0]*v[0]+v[1]*v[1]+v[2]*v[2]+v[3]*v[3];
    #pragma unroll
    for (int m = 32; m >= 1; m >>= 1) { s += __shfl_xor(s, m, 64); sq += __shfl_xor(sq, m, 64); }
    float* red = (float*)shbuf;
    int lane = t & 63, wv = t >> 6;
    if (lane == 0) { red[wv] = s; red[wv+3] = sq; }
    __syncthreads();
    s  = red[0]+red[1]+red[2];
    sq = red[3]+red[4]+red[5];
    float mean = s * (1.f/768.f);
    float var  = fmaxf(sq * (1.f/768.f) - mean*mean, 0.f);
    float inv  = rsqrtf(var + 1e-6f);
    float4 wq_ = ((const float4*)w)[t];
    float4 bq_ = ((const float4*)b)[t];
    u16 o[4];
    o[0] = f2bf((v[0]-mean)*inv*wq_.x + bq_.x);
    o[1] = f2bf((v[1]-mean)*inv*wq_.y + bq_.y);
    o[2] = f2bf((v[2]-mean)*inv*wq_.z + bq_.z);
    o[3] = f2bf((v[3]-mean)*inv*wq_.w + bq_.w);
    *(ushort4*)(dst + t*4) = make_ushort4(o[0], o[1], o[2], o[3]);
    return;
  }
  const int pid = bx - 2*NROWS;           // 0..1727
  const int z   = pid / 576;              // 0,1,2
  const int rem = pid - z*576;            // 0..575
  if (z == 2) {                           // ---- build [128][768] woaT = [w_off|w_attn|0]^T ----
    int idx = rem*192 + t;
    if (idx >= 128*CDIM) return;
    int n = idx / CDIM, k = idx - n*CDIM;
    float v = 0.f;
    if (n < 48)      v = woff[(size_t)k*48 + n];
    else if (n < 72) v = wattn[(size_t)k*24 + (n-48)];
    woaT[idx] = f2bf(v);
    return;
  }
  // ---- transpose w_value / w_out [K][N] -> [N][K] to bf16 ----
  u16* tile = (u16*)shbuf;                // [32][33]
  const float* in = z ? wo_ : wv_;
  u16* out        = z ? woT : wvT;
  int bn = (rem % 24) * 32;
  int bk = (rem / 24) * 32;
  int tx = t & 31, ty = t >> 5;           // ty 0..5
  for (int i = ty; i < 32; i += 6)
    tile[i*33 + tx] = f2bf(in[(size_t)(bk+i)*CDIM + bn + tx]);
  __syncthreads();
  for (int i = ty; i < 32; i += 6)
    out[(size_t)(bn+i)*CDIM + bk + tx] = tile[tx*33 + i];
}

// ---------------- fused GEMM 0+1: grid (64, 20) ----------------
// y<12 : value GEMM  C=A_f*wvT^T tile 128x64, full K, EPI0 bf16+b_value
// y>=12: off/attn GEMM A_q*woaT^T, n0=((y-12)&1)*64, split-K z=(y-12)>>1 (K-chunk 192),
//        EPI1 f32 partials [z][8192][72], bias folded into z==0
__global__ __launch_bounds__(256) void gemm01(
    const u16* __restrict__ Af, const u16* __restrict__ Aq,
    const u16* __restrict__ wvT, const u16* __restrict__ woaT,
    u16* __restrict__ val_bf, float* __restrict__ offawp,
    const float* __restrict__ b_value, const float* __restrict__ b_off,
    const float* __restrict__ b_attn) {
  __shared__ __align__(16) u16 smem[12288];  // 24 KB: As 2x4096 | Bs 2x2048; Cs[128][64] aliases
  u16* As = smem;
  u16* Bs = smem + 8192;
  u16* Cs = smem;
  const int m0 = blockIdx.x * 128;
  const bool isVal = blockIdx.y < 12;
  const int g  = blockIdx.y - 12;
  const int n0 = isVal ? blockIdx.y * 64 : (g & 1) * 64;
  const int zz = isVal ? 0 : (g >> 1);
  const int kbase = isVal ? 0 : zz * (CDIM / KS1);
  const int kend  = kbase + (isVal ? CDIM : CDIM / KS1);
  const u16* A  = isVal ? Af : Aq;
  const u16* Bt = isVal ? wvT : woaT;
  const int t = threadIdx.x, lane = t & 63, wv = t >> 6;
  const int wm = wv & 1, wn = wv >> 1;
  const int lrow = lane >> 2;
  const int lcol = (lane & 3) * 8;
  f32x4 acc[4][2] = {};

  for (int k0 = kbase; k0 < kend; k0 += 64) {
    #pragma unroll
    for (int j = 0; j < 4; ++j) {                  // A: 16 1KB segments (2 panels x 8)
      int gg = wv*4 + j;
      int p = gg >> 3, s = gg & 7;
      load_lds16(A + (size_t)(m0 + s*16 + lrow)*CDIM + k0 + p*32 + lcol,
                 As + p*4096 + s*512);
    }
    #pragma unroll
    for (int j = 0; j < 2; ++j) {                  // B: 8 segments (2 panels x 4)
      int gg = wv*2 + j;
      int p = gg >> 2, s = gg & 3;
      load_lds16(Bt + (size_t)(n0 + s*16 + lrow)*CDIM + k0 + p*32 + lcol,
                 Bs + p*2048 + s*512);
    }
    __syncthreads();
    #pragma unroll
    for (int u = 0; u < 2; ++u) {
      bf16x8 af[4], bfr[2];
      const int kc = (lane >> 4) * 8;
      #pragma unroll
      for (int i = 0; i < 4; ++i)
        af[i]  = *(const bf16x8*)(As + u*4096 + (wm*64 + i*16 + (lane & 15))*32 + kc);
      #pragma unroll
      for (int j = 0; j < 2; ++j)
        bfr[j] = *(const bf16x8*)(Bs + u*2048 + (wn*32 + j*16 + (lane & 15))*32 + kc);
      #pragma unroll
      for (int i = 0; i < 4; ++i)
        #pragma unroll
        for (int j = 0; j < 2; ++j)
          acc[i][j] = __builtin_amdgcn_mfma_f32_16x16x32_bf16(af[i], bfr[j], acc[i][j], 0, 0, 0);
    }
    __syncthreads();
  }

  const int r0 = (lane >> 4) * 4;    // C/D: col=lane&15, row=(lane>>4)*4+reg  [m89/m91]
  const int c  = lane & 15;

  if (!isVal) {                      // EPI1: scattered f32 partials (72 live cols)
    float* op = offawp + (size_t)zz * NROWS * 72;
    #pragma unroll
    for (int i = 0; i < 4; ++i)
      #pragma unroll
      for (int j = 0; j < 2; ++j) {
        int col = n0 + wn*32 + j*16 + c;
        if (col < 72) {
          float bb = 0.f;
          if (zz == 0) bb = (col < 48) ? b_off[col] : b_attn[col-48];
          #pragma unroll
          for (int r = 0; r < 4; ++r)
            op[(size_t)(m0 + wm*64 + i*16 + r0 + r)*72 + col] = acc[i][j][r] + bb;
        }
      }
    return;
  }

  // EPI0: stage (acc + b_value) bf16 into Cs, coalesced 16B stores
  #pragma unroll
  for (int i = 0; i < 4; ++i)
    #pragma unroll
    for (int j = 0; j < 2; ++j) {
      int col = wn*32 + j*16 + c;
      float bb = b_value[n0 + col];
      #pragma unroll
      for (int r = 0; r < 4; ++r)
        Cs[(wm*64 + i*16 + r0 + r)*64 + col] = f2bf(acc[i][j][r] + bb);
    }
  __syncthreads();
  #pragma unroll
  for (int it = 0; it < 4; ++it) {
    int idx = it*256 + t;
    int row = idx >> 3, colb = (idx & 7) * 8;
    *(bf16x8*)(val_bf + (size_t)(m0 + row)*CDIM + n0 + colb) = *(const bf16x8*)(Cs + row*64 + colb);
  }
}

// ---------------- output GEMM: C = samp*woT^T, out = x + gamma*(C + b_out), f32 ----------------
__global__ __launch_bounds__(256) void gemm2(
    const u16* __restrict__ A, const u16* __restrict__ Bt, float* __restrict__ Cout,
    const float* __restrict__ bias0, const float* __restrict__ xres,
    const float* __restrict__ gammap) {
  __shared__ __align__(16) u16 smem[12288];
  u16* As = smem;
  u16* Bs = smem + 8192;
  u16* Cs = smem;
  const int m0 = blockIdx.x * 128;
  const int n0 = blockIdx.y * 64;
  const int t = threadIdx.x, lane = t & 63, wv = t >> 6;
  const int wm = wv & 1, wn = wv >> 1;
  const int lrow = lane >> 2;
  const int lcol = (lane & 3) * 8;
  f32x4 acc[4][2] = {};

  for (int k0 = 0; k0 < CDIM; k0 += 64) {
    #pragma unroll
    for (int j = 0; j < 4; ++j) {
      int gg = wv*4 + j;
      int p = gg >> 3, s = gg & 7;
      load_lds16(A + (size_t)(m0 + s*16 + lrow)*CDIM + k0 + p*32 + lcol,
                 As + p*4096 + s*512);
    }
    #pragma unroll
    for (int j = 0; j < 2; ++j) {
      int gg = wv*2 + j;
      int p = gg >> 2, s = gg & 3;
      load_lds16(Bt + (size_t)(n0 + s*16 + lrow)*CDIM + k0 + p*32 + lcol,
                 Bs + p*2048 + s*512);
    }
    __syncthreads();
    #pragma unroll
    for (int u = 0; u < 2; ++u) {
      bf16x8 af[4], bfr[2];
      const int kc = (lane >> 4) * 8;
      #pragma unroll
      for (int i = 0; i < 4; ++i)
        af[i]  = *(const bf16x8*)(As + u*4096 + (wm*64 + i*16 + (lane & 15))*32 + kc);
      #pragma unroll
      for (int j = 0; j < 2; ++j)
        bfr[j] = *(const bf16x8*)(Bs + u*2048 + (wn*32 + j*16 + (lane & 15))*32 + kc);
      #pragma unroll
      for (int i = 0; i < 4; ++i)
        #pragma unroll
        for (int j = 0; j < 2; ++j)
          acc[i][j] = __builtin_amdgcn_mfma_f32_16x16x32_bf16(af[i], bfr[j], acc[i][j], 0, 0, 0);
    }
    __syncthreads();
  }

  const int r0 = (lane >> 4) * 4;
  const int c  = lane & 15;
  #pragma unroll
  for (int i = 0; i < 4; ++i)
    #pragma unroll
    for (int j = 0; j < 2; ++j) {
      int col = wn*32 + j*16 + c;
      float bb = bias0[n0 + col];
      #pragma unroll
      for (int r = 0; r < 4; ++r)
        Cs[(wm*64 + i*16 + r0 + r)*64 + col] = f2bf(acc[i][j][r] + bb);
    }
  __syncthreads();
  #pragma unroll
  for (int it = 0; it < 4; ++it) {
    int idx = it*256 + t;
    int row = idx >> 3, colb = (idx & 7) * 8;
    size_t gbase = (size_t)(m0 + row)*CDIM + n0 + colb;
    const u16* cp = Cs + row*64 + colb;
    const float* xp = xres + gbase;
    const float* gp = gammap + n0 + colb;
    float4 x0 = *(const float4*)xp,  x1 = *(const float4*)(xp + 4);
    float4 g0 = *(const float4*)gp,  g1 = *(const float4*)(gp + 4);
    float4 o0, o1;
    o0.x = x0.x + g0.x*bf2f(cp[0]); o0.y = x0.y + g0.y*bf2f(cp[1]);
    o0.z = x0.z + g0.z*bf2f(cp[2]); o0.w = x0.w + g0.w*bf2f(cp[3]);
    o1.x = x1.x + g1.x*bf2f(cp[4]); o1.y = x1.y + g1.y*bf2f(cp[5]);
    o1.z = x1.z + g1.z*bf2f(cp[6]); o1.w = x1.w + g1.w*bf2f(cp[7]);
    *(float4*)(Cout + gbase)     = o0;
    *(float4*)(Cout + gbase + 4) = o1;
  }
}

// ---------------- deformable sampling: wave handles 2 heads of one row, 32-load burst ----------------
__global__ __launch_bounds__(256) void sample_kernel(
    const u16* __restrict__ value,   // [B*4096][768] bf16, col = h*128+d
    const float* __restrict__ offawp,// [KS1][8192][72] f32 K-partials
    const float* __restrict__ refp,  // [8192][2] f32
    u16* __restrict__ out) {
  const int wq   = blockIdx.x * 4 + (threadIdx.x >> 6);  // 0..24575
  const int lane = threadIdx.x & 63;
  const int row  = wq / 3;
  const int h0   = (wq % 3) * 2;      // 0,2,4
  const int b    = row >> 12;
  const float* pr = offawp + (size_t)row*72;
  float rx = refp[(size_t)row*2]   * 64.f - 0.5f;
  float ry = refp[(size_t)row*2+1] * 64.f - 0.5f;

  float wts[2][16]; int offs[2][16];
  #pragma unroll
  for (int s = 0; s < 2; ++s) {
    const int h = h0 + s;
    float ob[8], aw4[4];
    #pragma unroll
    for (int k = 0; k < 8; ++k) {
      float v = 0.f;
      #pragma unroll
      for (int z = 0; z < KS1; ++z) v += pr[(size_t)z*NROWS*72 + h*8 + k];
      ob[k] = v;
    }
    #pragma unroll
    for (int k = 0; k < 4; ++k) {
      float v = 0.f;
      #pragma unroll
      for (int z = 0; z < KS1; ++z) v += pr[(size_t)z*NROWS*72 + 48 + h*4 + k];
      aw4[k] = v;
    }
    float mx = fmaxf(fmaxf(aw4[0],aw4[1]), fmaxf(aw4[2],aw4[3]));
    float e0 = __expf(aw4[0]-mx), e1 = __expf(aw4[1]-mx), e2 = __expf(aw4[2]-mx), e3 = __expf(aw4[3]-mx);
    float rs = 1.f / (e0+e1+e2+e3);
    float awt[4] = {e0*rs, e1*rs, e2*rs, e3*rs};
    #pragma unroll
    for (int p = 0; p < 4; ++p) {
      float px = rx + ob[p*2];
      float py = ry + ob[p*2+1];
      float x0f = floorf(px), y0f = floorf(py);
      float fx = px - x0f, fy = py - y0f;
      int x0 = (int)x0f, y0 = (int)y0f;
      #pragma unroll
      for (int dy = 0; dy < 2; ++dy)
        #pragma unroll
        for (int dx = 0; dx < 2; ++dx) {
          int yi = y0 + dy, xi = x0 + dx;
          bool valid = (yi >= 0) & (yi < 64) & (xi >= 0) & (xi < 64);
          float wt = (dy ? fy : 1.f-fy) * (dx ? fx : 1.f-fx) * awt[p];
          wts[s][p*4+dy*2+dx] = valid ? wt : 0.f;
          int yc = min(max(yi, 0), 63), xc = min(max(xi, 0), 63);
          offs[s][p*4+dy*2+dx] = (yc*64 + xc) * 384;
        }
    }
  }
  const u32* vbase = (const u32*)value + (size_t)b*4096*384 + h0*64 + lane;
  u32 vals[2][16];
  #pragma unroll
  for (int s = 0; s < 2; ++s)
    #pragma unroll
    for (int i = 0; i < 16; ++i)
      vals[s][i] = (vbase + s*64)[offs[s][i]];   // 32 loads in flight
  #pragma unroll
  for (int s = 0; s < 2; ++s) {
    float accx = 0.f, accy = 0.f;
    #pragma unroll
    for (int i = 0; i < 16; ++i) {
      accx += wts[s][i] * bf2f((u16)(vals[s][i] & 0xffffu));
      accy += wts[s][i] * bf2f((u16)(vals[s][i] >> 16));
    }
    ((u32*)out)[(size_t)row*384 + (h0+s)*64 + lane] = (u32)f2bf(accx) | ((u32)f2bf(accy) << 16);
  }
}

extern "C" void kernel_launch(void* const* d_in, const int* in_sizes, int n_in,
                              void* d_out, int out_size, void* d_ws, size_t ws_size,
                              hipStream_t stream) {
  const float* x       = (const float*)d_in[0];
  const float* refp    = (const float*)d_in[1];
  const float* feat    = (const float*)d_in[2];
  const float* qn_w    = (const float*)d_in[5];
  const float* qn_b    = (const float*)d_in[6];
  const float* fn_w    = (const float*)d_in[7];
  const float* fn_b    = (const float*)d_in[8];
  const float* gamma   = (const float*)d_in[9];
  const float* w_value = (const float*)d_in[10];
  const float* b_value = (const float*)d_in[11];
  const float* w_off   = (const float*)d_in[12];
  const float* b_off   = (const float*)d_in[13];
  const float* w_attn  = (const float*)d_in[14];
  const float* b_attn  = (const float*)d_in[15];
  const float* w_out   = (const float*)d_in[16];
  const float* b_out   = (const float*)d_in[17];

  char* p = (char*)d_ws;
  const size_t act = (size_t)NROWS * CDIM * 2;       // 12.58 MB
  u16* q_bf   = (u16*)p; p += act;
  u16* f_bf   = (u16*)p; p += act;
  u16* val_bf = (u16*)p; p += act;
  u16* wvT    = (u16*)p; p += (size_t)CDIM*CDIM*2;
  u16* woT    = (u16*)p; p += (size_t)CDIM*CDIM*2;
  u16* woaT   = (u16*)p; p += (size_t)128*CDIM*2;
  float* offawp = (float*)p; p += (size_t)KS1*NROWS*72*4;
  u16* samp_bf = q_bf;   // q_bf dead after gemm01; reuse

  pre_kernel<<<dim3(2*NROWS + 1728), 192, 0, stream>>>(
      x, feat, qn_w, qn_b, fn_w, fn_b, w_value, w_out, w_off, w_attn,
      q_bf, f_bf, wvT, woT, woaT);
  gemm01<<<dim3(64, 20), 256, 0, stream>>>(
      f_bf, q_bf, wvT, woaT, val_bf, offawp, b_value, b_off, b_attn);
  sample_kernel<<<dim3(6144), 256, 0, stream>>>(val_bf, offawp, refp, samp_bf);
  gemm2<<<dim3(64, 12), 256, 0, stream>>>(samp_bf, woT, (float*)d_out, b_out, x, gamma);
}